// Round 1
// baseline (98.193 us; speedup 1.0000x reference)
//
#include <hip/hip_runtime.h>

// Problem constants
#define DD 20          // hypervol spatial extent per axis
#define MM 32          // channel count m
#define OO 19          // output extent per axis (DD - RANK + 1, RANK=2)
#define NWIN (OO*OO*OO)                  // 6859 windows
// Pair tasks: per (a,b) there are 9 c-pairs (c=0,2,..,16 with c+1) + 1 singleton (c=18)
#define TPAB 10
#define NTASK (OO*OO*TPAB)               // 3610 wave-tasks
#define WPB 4                            // tasks per block (one per wave)
#define NBLK ((NTASK + WPB - 1) / WPB)   // 903 blocks

// Lane mapping used by spatial_kernel: lane -> (i = lane&31, h = lane>>5),
// lane's j-range = [h*16, h*16+16). All tables are stored LANE-SWIZZLED so
// that a wave's float4 table read is one contiguous 1KB transaction:
//   CS[k][q][lane][e] = cos(2*pi*k / (i*32 + (h*16 + q*4 + e) + 2))
//   PS[q][lane][e]    = P [i][h*16 + q*4 + e]
//   MS[q][lane][e]    = Mw[i][h*16 + q*4 + e] / 16
#define CS_FLOATS (OO*MM*MM)             // 19456
#define PS_OFF CS_FLOATS                 // 19456
#define MS_OFF (PS_OFF + MM*MM)          // 20480
#define WS_FLOATS (MS_OFF + MM*MM)       // 21504

// per-wave LDS slice: S1 (640) | S2 (640) | W (608); X1 aliases dead S1,
// X2 aliases dead S2. 4 waves * 1888 * 4B = 30208 B/block -> still 4 blocks/CU.
#define LSLICE 1888
#define S2OFF 640
#define WOFF 1280

#define ACC4(d, s) { (d).x += (s).x; (d).y += (s).y; (d).z += (s).z; (d).w += (s).w; }

__global__ __launch_bounds__(256) void build_tables_kernel(
        const float* __restrict__ Mw, const float* __restrict__ P,
        float* __restrict__ ws) {
    const int idx = blockIdx.x * 256 + threadIdx.x;
    if (idx < CS_FLOATS) {
        const int k    = idx >> 10;          // 0..18
        const int r    = idx & 1023;
        const int q    = r >> 8;             // 0..3
        const int lane = (r >> 2) & 63;
        const int e    = r & 3;
        const int i    = lane & 31;
        const int j    = (lane >> 5) * 16 + q * 4 + e;
        const float period = (float)(i * MM + j + 2);
        ws[idx] = cosf(6.28318530717958647692f * (float)k / period);
    } else if (idx < WS_FLOATS) {
        const int r    = (idx - PS_OFF) & 1023;
        const int q    = r >> 8;
        const int lane = (r >> 2) & 63;
        const int e    = r & 3;
        const int i    = lane & 31;
        const int j    = (lane >> 5) * 16 + q * 4 + e;
        ws[idx] = (idx < MS_OFF) ? P[i * MM + j]
                                 : Mw[i * MM + j] * 0.0625f;
    }
}

// Wave-internal sync: LDS-counter drain only + compiler fence. No s_barrier,
// no vmcnt drain -> waves never convoy, global loads stay in flight.
__device__ __forceinline__ void lds_sync() {
    __builtin_amdgcn_s_waitcnt(0xC07F);   // lgkmcnt(0) only
    __builtin_amdgcn_wave_barrier();
}

// One WAVE per c-PAIR of windows (a,b,c)+(a,b,c+1): shares the 4 middle H-rows
// (12 row-loads instead of 16), shares mt/qab/t2c table state, and halves the
// wave count (3612 waves -> fully resident in ONE round, waves drift apart so
// VMEM / LDS / VALU bursts de-convoy). Per-window arithmetic order is kept
// bit-identical to the 1-window-per-wave version.
// launch_bounds min-waves MUST stay 4: phase 3 needs 48 persistent VGPRs
// (+16 qab); (256,5) capped VGPR at 102 and spilled (prev session R6: 44.5us).
__global__ __launch_bounds__(256, 4) void spatial_kernel(
        const float* __restrict__ H, const float* __restrict__ ws,
        float* __restrict__ out) {
    __shared__ __align__(16) float sLDS[WPB][LSLICE];

    const int tid  = threadIdx.x;
    const int w    = tid >> 6;
    const int lane = tid & 63;
    const int i    = lane & 31;
    const int h    = lane >> 5;
    const int jb   = h * 16;

    // XCD-contiguous block swizzle (903 = 7*113 + 1*112, bijective)
    const int raw = blockIdx.x;
    const int xcd = raw & 7;
    const int kk  = raw >> 3;
    const int sb  = (xcd < 7) ? (xcd * 113 + kk) : (791 + kk);
    const int task = sb * WPB + w;
    if (task >= NTASK) return;           // wave-uniform; no block barriers exist

    const int q  = task % TPAB;          // 0..9
    const int ab = task / TPAB;
    const int b  = ab % OO;
    const int a  = ab / OO;
    const int c  = q * 2;                // q<9: pair (c, c+1); q==9: single c=18
    const bool paired = (q < 9);
    const int win1 = (a * OO + b) * OO + c;

    const float4* __restrict__ T = (const float4*)ws;   // all tables, float4 units
    float* __restrict__ S1 = sLDS[w];
    float* __restrict__ S2 = sLDS[w] + S2OFF;
    float* __restrict__ W  = sLDS[w] + WOFF;
    float* __restrict__ X1 = sLDS[w];          // aliases dead S1
    float* __restrict__ X2 = sLDS[w] + S2OFF;  // aliases dead S2

    // hoist Mw row (pre-scaled by 1/16): 4 coalesced dwordx4, in flight with H
    float mt[16];
    #pragma unroll
    for (int qq = 0; qq < 4; ++qq) {
        const float4 v = T[(MS_OFF >> 2) + qq * 64 + lane];
        mt[qq*4+0] = v.x; mt[qq*4+1] = v.y; mt[qq*4+2] = v.z; mt[qq*4+3] = v.w;
    }

    // ---- phase 1: shared 12-row load, two 8-shift pre-sums (bit-identical
    //      per-window add order: row(da,db,c) then row(da,db,c+1) per (da,db)) ----
    {
        float4 a10 = make_float4(0.f, 0.f, 0.f, 0.f);
        float4 a11 = a10, a12 = a10;
        float4 a20 = a10, a21 = a10, a22 = a10;
        #pragma unroll
        for (int da = 0; da < 2; ++da)
            #pragma unroll
            for (int db = 0; db < 2; ++db) {
                const float* rb = H + (size_t)((((a + da) * DD + (b + db)) * DD + c) * DD) * MM;
                const float4* __restrict__ p0 = (const float4*)rb;              // c
                const float4* __restrict__ p1 = (const float4*)(rb + DD * MM);  // c+1
                const float4* __restrict__ p2 = (const float4*)(rb + 2 * DD * MM); // c+2
                const float4 u0 = p0[lane],      u1 = p0[64 + lane];
                const float4 v0 = p1[lane],      v1 = p1[64 + lane];
                ACC4(a10, u0); ACC4(a10, v0);
                ACC4(a11, u1); ACC4(a11, v1);
                if (paired) {
                    const float4 t0 = p2[lane], t1 = p2[64 + lane];
                    ACC4(a20, v0); ACC4(a20, t0);
                    ACC4(a21, v1); ACC4(a21, t1);
                }
                if (lane < 32) {
                    const float4 u2 = p0[128 + lane], v2 = p1[128 + lane];
                    ACC4(a12, u2); ACC4(a12, v2);
                    if (paired) {
                        const float4 t2 = p2[128 + lane];
                        ACC4(a22, v2); ACC4(a22, t2);
                    }
                }
            }
        float4* s1v = (float4*)S1;
        s1v[lane] = a10; s1v[64 + lane] = a11;
        if (lane < 32) s1v[128 + lane] = a12;
        if (paired) {
            float4* s2v = (float4*)S2;
            s2v[lane] = a20; s2v[64 + lane] = a21;
            if (lane < 32) s2v[128 + lane] = a22;
        }
    }
    lds_sync();

    // ---- phase 1.5: W[d][j] = S[d][j] + S[d+1][j]  (1/16 folded into mt) ----
    auto p15 = [&](const float* __restrict__ Sx) {
        #pragma unroll
        for (int t = 0; t < 10; ++t) {
            const int idx = t * 64 + lane;
            if (idx < OO * MM)
                W[idx] = Sx[idx] + Sx[idx + MM];
        }
    };

    // ---- phase 2: x[d][i] = sum_j W[d][j] * Mw[i][j]/16 (j-half + shfl) ----
    auto p2f = [&](float* __restrict__ Xx) {
        #pragma unroll
        for (int d = 0; d < OO; ++d) {
            const float4* __restrict__ wr = (const float4*)(W + d * MM + jb);
            float t = 0.f;
            #pragma unroll
            for (int qq = 0; qq < 4; ++qq) {
                const float4 v = wr[qq];
                t += v.x * mt[qq*4+0] + v.y * mt[qq*4+1]
                   + v.z * mt[qq*4+2] + v.w * mt[qq*4+3];
            }
            t += __shfl_xor(t, 32, 64);
            if (h == 0) Xx[d * MM + i] = t;
        }
    };

    p15(S1);
    lds_sync();
    p2f(X1);
    lds_sync();

    // ---- phase 3 init (window 1): qab = P*Ca*Cb persists for window 2 ----
    float qab[16], s0[16], s1[16], t2c[16];
    #pragma unroll
    for (int qq = 0; qq < 4; ++qq) {
        const float4 pv = T[(PS_OFF >> 2) + qq * 64 + lane];
        const float4 va = T[(a * 4 + qq) * 64 + lane];
        const float4 vb = T[(b * 4 + qq) * 64 + lane];
        const float4 vc = T[(c * 4 + qq) * 64 + lane];
        const float4 c1 = T[(1 * 4 + qq) * 64 + lane];
        const float qx = pv.x * va.x * vb.x;
        const float qy = pv.y * va.y * vb.y;
        const float qz = pv.z * va.z * vb.z;
        const float qw = pv.w * va.w * vb.w;
        qab[qq*4+0] = qx; s1[qq*4+0] = qx * vc.x; s0[qq*4+0] = s1[qq*4+0] * c1.x; t2c[qq*4+0] = c1.x + c1.x;
        qab[qq*4+1] = qy; s1[qq*4+1] = qy * vc.y; s0[qq*4+1] = s1[qq*4+1] * c1.y; t2c[qq*4+1] = c1.y + c1.y;
        qab[qq*4+2] = qz; s1[qq*4+2] = qz * vc.z; s0[qq*4+2] = s1[qq*4+2] * c1.z; t2c[qq*4+2] = c1.z + c1.z;
        qab[qq*4+3] = qw; s1[qq*4+3] = qw * vc.w; s0[qq*4+3] = s1[qq*4+3] * c1.w; t2c[qq*4+3] = c1.w + c1.w;
    }

    // ---- phase 3: out[d][i] = sum_j x[d][j]*qp[i][j]*cos(w_ij*d) ----
    auto p3f = [&](const float* __restrict__ Xx, size_t obase) {
        #pragma unroll
        for (int d = 0; d < OO; ++d) {
            const float4* __restrict__ xr = (const float4*)(Xx + d * MM + jb);
            float t = 0.f;
            #pragma unroll
            for (int qq = 0; qq < 4; ++qq) {
                const float4 v = xr[qq];
                t += v.x * s1[qq*4+0] + v.y * s1[qq*4+1]
                   + v.z * s1[qq*4+2] + v.w * s1[qq*4+3];
            }
            #pragma unroll
            for (int jj = 0; jj < 16; ++jj) {     // advance recurrence
                const float nx = __builtin_fmaf(t2c[jj], s1[jj], -s0[jj]);
                s0[jj] = s1[jj];
                s1[jj] = nx;
            }
            t += __shfl_xor(t, 32, 64);
            if (h == 0) out[obase + d * MM + i] = t;
        }
    };

    // Region 4: issue vc2 loads (VMEM) + window-2 phase 1.5 (LDS: reads S2,
    // writes W -- dead after p2f(X1)) overlapped with window-1 phase 3 (VALU).
    float4 vc2[4];
    if (paired) {
        #pragma unroll
        for (int qq = 0; qq < 4; ++qq)
            vc2[qq] = T[((c + 1) * 4 + qq) * 64 + lane];
        p15(S2);
    }
    p3f(X1, (size_t)win1 * (OO * MM));
    if (paired) {
        lds_sync();
        // window-2 phase 3 init: reuse qab, t2c; c1 == 0.5*t2c exactly
        #pragma unroll
        for (int qq = 0; qq < 4; ++qq) {
            s1[qq*4+0] = qab[qq*4+0] * vc2[qq].x; s0[qq*4+0] = s1[qq*4+0] * (0.5f * t2c[qq*4+0]);
            s1[qq*4+1] = qab[qq*4+1] * vc2[qq].y; s0[qq*4+1] = s1[qq*4+1] * (0.5f * t2c[qq*4+1]);
            s1[qq*4+2] = qab[qq*4+2] * vc2[qq].z; s0[qq*4+2] = s1[qq*4+2] * (0.5f * t2c[qq*4+2]);
            s1[qq*4+3] = qab[qq*4+3] * vc2[qq].w; s0[qq*4+3] = s1[qq*4+3] * (0.5f * t2c[qq*4+3]);
        }
        p2f(X2);
        lds_sync();
        p3f(X2, (size_t)(win1 + 1) * (OO * MM));
    }
}

extern "C" void kernel_launch(void* const* d_in, const int* in_sizes, int n_in,
                              void* d_out, int out_size, void* d_ws, size_t ws_size,
                              hipStream_t stream) {
    const float* H  = (const float*)d_in[0];   // hypervol [20,20,20,20,32]
    const float* Mw = (const float*)d_in[1];   // M_w [32,32]
    const float* P  = (const float*)d_in[2];   // P   [32,32]
    float* out = (float*)d_out;
    float* ws  = (float*)d_ws;

    build_tables_kernel<<<WS_FLOATS / 256, 256, 0, stream>>>(Mw, P, ws);  // 84 blocks
    spatial_kernel<<<NBLK, 256, 0, stream>>>(H, ws, out);
}

// Round 2
// 95.776 us; speedup vs baseline: 1.0252x; 1.0252x over previous
//
#include <hip/hip_runtime.h>

// Problem constants
#define DD 20          // hypervol spatial extent per axis
#define MM 32          // channel count m
#define OO 19          // output extent per axis (DD - RANK + 1, RANK=2)
#define NWIN (OO*OO*OO)                  // 6859 windows
#define WPB 4                            // windows per block (one per wave)
#define NBLK ((NWIN + WPB - 1) / WPB)    // 1715 blocks

// Lane mapping used by spatial_kernel: lane -> (i = lane&31, h = lane>>5),
// lane's j-range = [h*16, h*16+16). All tables are stored LANE-SWIZZLED so
// that a wave's float4 table read is one contiguous 1KB transaction:
//   CS[k][q][lane][e] = cos(2*pi*k / (i*32 + (h*16 + q*4 + e) + 2))
//   PS[q][lane][e]    = P [i][h*16 + q*4 + e]
//   MS[q][lane][e]    = Mw[i][h*16 + q*4 + e] / 16
#define CS_FLOATS (OO*MM*MM)             // 19456
#define PS_OFF CS_FLOATS                 // 19456
#define MS_OFF (PS_OFF + MM*MM)          // 20480
#define WS_FLOATS (MS_OFF + MM*MM)       // 21504

// per-wave LDS slice: S (640 floats, aliased by X after phase 1.5) + W (608)
#define LSLICE 1248
#define WOFF 640

__global__ __launch_bounds__(256) void build_tables_kernel(
        const float* __restrict__ Mw, const float* __restrict__ P,
        float* __restrict__ ws) {
    const int idx = blockIdx.x * 256 + threadIdx.x;
    if (idx < CS_FLOATS) {
        const int k    = idx >> 10;          // 0..18
        const int r    = idx & 1023;
        const int q    = r >> 8;             // 0..3
        const int lane = (r >> 2) & 63;
        const int e    = r & 3;
        const int i    = lane & 31;
        const int j    = (lane >> 5) * 16 + q * 4 + e;
        const float period = (float)(i * MM + j + 2);
        ws[idx] = cosf(6.28318530717958647692f * (float)k / period);
    } else if (idx < WS_FLOATS) {
        const int r    = (idx - PS_OFF) & 1023;
        const int q    = r >> 8;
        const int lane = (r >> 2) & 63;
        const int e    = r & 3;
        const int i    = lane & 31;
        const int j    = (lane >> 5) * 16 + q * 4 + e;
        ws[idx] = (idx < MS_OFF) ? P[i * MM + j]
                                 : Mw[i * MM + j] * 0.0625f;
    }
}

// Wave-internal sync: LDS-counter drain only + compiler fence. No s_barrier,
// no vmcnt drain -> waves never convoy, global loads stay in flight.
__device__ __forceinline__ void lds_sync() {
    __builtin_amdgcn_s_waitcnt(0xC07F);   // lgkmcnt(0) only
    __builtin_amdgcn_wave_barrier();
}

// One WAVE per (a,b,c) window; 4 independent windows per block.
// Phase 3: Chebyshev recurrence s_d = 2cosw*s_{d-1} - s_{d-2}, qp in init.
// launch_bounds min-waves MUST stay 4: phase 3 needs 48 persistent VGPRs;
// (256,5) capped VGPR at 102 and spilled the recurrence state (R6: 44.5us).
__global__ __launch_bounds__(256, 4) void spatial_kernel(
        const float* __restrict__ H, const float* __restrict__ ws,
        float* __restrict__ out) {
    __shared__ __align__(16) float sLDS[WPB][LSLICE];

    const int tid  = threadIdx.x;
    const int w    = tid >> 6;
    const int lane = tid & 63;
    const int i    = lane & 31;
    const int h    = lane >> 5;
    const int jb   = h * 16;

    // XCD-contiguous block swizzle (1715 = 3*215 + 5*214, bijective)
    const int raw = blockIdx.x;
    const int xcd = raw & 7;
    const int k   = raw >> 3;
    const int sb  = (xcd < 3) ? (xcd * 215 + k) : (645 + (xcd - 3) * 214 + k);
    const int win = sb * WPB + w;
    if (win >= NWIN) return;             // wave-uniform; no block barriers exist
    const int c = win % OO;
    const int b = (win / OO) % OO;
    const int a = win / (OO * OO);

    const float4* __restrict__ T = (const float4*)ws;   // all tables, float4 units
    float* __restrict__ S = sLDS[w];          // phase 1 pre-sums (640 floats)
    float* __restrict__ W = sLDS[w] + WOFF;   // raw window sums  (608 floats)
    float* __restrict__ X = sLDS[w];          // x rows -- aliases dead S

    // hoist Mw row (pre-scaled by 1/16): 4 coalesced dwordx4, in flight with H
    float mt[16];
    #pragma unroll
    for (int q = 0; q < 4; ++q) {
        const float4 v = T[(MS_OFF >> 2) + q * 64 + lane];
        mt[q*4+0] = v.x; mt[q*4+1] = v.y; mt[q*4+2] = v.z; mt[q*4+3] = v.w;
    }

    // ---- phase 1: 8-shift (a,b,c) pre-sum, 640 floats, float4 ----
    {
        float4 a0 = make_float4(0.f, 0.f, 0.f, 0.f);
        float4 a1 = a0, a2 = a0;
        #pragma unroll
        for (int da = 0; da < 2; ++da)
            #pragma unroll
            for (int db = 0; db < 2; ++db)
                #pragma unroll
                for (int dc = 0; dc < 2; ++dc) {
                    const float4* __restrict__ p = (const float4*)(
                        H + (size_t)((((a + da) * DD + (b + db)) * DD + (c + dc)) * DD) * MM);
                    const float4 v0 = p[lane];
                    const float4 v1 = p[64 + lane];
                    a0.x += v0.x; a0.y += v0.y; a0.z += v0.z; a0.w += v0.w;
                    a1.x += v1.x; a1.y += v1.y; a1.z += v1.z; a1.w += v1.w;
                    if (lane < 32) {
                        const float4 v2 = p[128 + lane];
                        a2.x += v2.x; a2.y += v2.y; a2.z += v2.z; a2.w += v2.w;
                    }
                }
        ((float4*)S)[lane]      = a0;
        ((float4*)S)[64 + lane] = a1;
        if (lane < 32) ((float4*)S)[128 + lane] = a2;
    }
    lds_sync();

    // ---- phase 1.5: W[d][j] = S[d][j] + S[d+1][j]  (1/16 folded into mt) ----
    #pragma unroll
    for (int t = 0; t < 10; ++t) {
        const int idx = t * 64 + lane;
        if (idx < OO * MM)
            W[idx] = S[idx] + S[idx + MM];
    }
    lds_sync();

    // ---- phase 2: x[d][i] = sum_j W[d][j] * Mw[i][j]/16 (j-half + shfl) ----
    #pragma unroll
    for (int d = 0; d < OO; ++d) {
        const float4* __restrict__ wr = (const float4*)(W + d * MM + jb);
        float t = 0.f;
        #pragma unroll
        for (int q = 0; q < 4; ++q) {
            const float4 v = wr[q];
            t += v.x * mt[q*4+0] + v.y * mt[q*4+1]
               + v.z * mt[q*4+2] + v.w * mt[q*4+3];
        }
        t += __shfl_xor(t, 32, 64);
        if (h == 0) X[d * MM + i] = t;       // X aliases dead S region
    }
    lds_sync();

    // ---- phase 3: out[d][i] = sum_j x[d][j]*qp[i][j]*cos(w_ij*d) ----
    // All table reads below are coalesced dwordx4 (lane-swizzled layout).
    float s0[16], s1[16], t2c[16];
    #pragma unroll
    for (int q = 0; q < 4; ++q) {
        const float4 pv = T[(PS_OFF >> 2) + q * 64 + lane];
        const float4 va = T[(a * 4 + q) * 64 + lane];
        const float4 vb = T[(b * 4 + q) * 64 + lane];
        const float4 vc = T[(c * 4 + q) * 64 + lane];
        const float4 c1 = T[(1 * 4 + q) * 64 + lane];
        const float qpx = pv.x * va.x * vb.x * vc.x;
        const float qpy = pv.y * va.y * vb.y * vc.y;
        const float qpz = pv.z * va.z * vb.z * vc.z;
        const float qpw = pv.w * va.w * vb.w * vc.w;
        s1[q*4+0] = qpx; s0[q*4+0] = qpx * c1.x; t2c[q*4+0] = c1.x + c1.x;
        s1[q*4+1] = qpy; s0[q*4+1] = qpy * c1.y; t2c[q*4+1] = c1.y + c1.y;
        s1[q*4+2] = qpz; s0[q*4+2] = qpz * c1.z; t2c[q*4+2] = c1.z + c1.z;
        s1[q*4+3] = qpw; s0[q*4+3] = qpw * c1.w; t2c[q*4+3] = c1.w + c1.w;
    }
    const size_t obase = (size_t)win * (OO * MM);
    #pragma unroll
    for (int d = 0; d < OO; ++d) {
        const float4* __restrict__ xr = (const float4*)(X + d * MM + jb);
        float t = 0.f;
        #pragma unroll
        for (int q = 0; q < 4; ++q) {
            const float4 v = xr[q];
            t += v.x * s1[q*4+0] + v.y * s1[q*4+1]
               + v.z * s1[q*4+2] + v.w * s1[q*4+3];
        }
        #pragma unroll
        for (int jj = 0; jj < 16; ++jj) {     // advance recurrence
            const float nx = __builtin_fmaf(t2c[jj], s1[jj], -s0[jj]);
            s0[jj] = s1[jj];
            s1[jj] = nx;
        }
        t += __shfl_xor(t, 32, 64);
        if (h == 0) out[obase + d * MM + i] = t;
    }
}

extern "C" void kernel_launch(void* const* d_in, const int* in_sizes, int n_in,
                              void* d_out, int out_size, void* d_ws, size_t ws_size,
                              hipStream_t stream) {
    const float* H  = (const float*)d_in[0];   // hypervol [20,20,20,20,32]
    const float* Mw = (const float*)d_in[1];   // M_w [32,32]
    const float* P  = (const float*)d_in[2];   // P   [32,32]
    float* out = (float*)d_out;
    float* ws  = (float*)d_ws;

    build_tables_kernel<<<WS_FLOATS / 256, 256, 0, stream>>>(Mw, P, ws);  // 84
    spatial_kernel<<<NBLK, 256, 0, stream>>>(H, ws, out);
}